// Round 1
// baseline (77.227 us; speedup 1.0000x reference)
//
#include <hip/hip_runtime.h>

// out = FWHT(in1 * in2) / sqrt(4096), rows of length N=4096, fp32.
// One row per 256-thread block; 16 elements/thread in registers.
// FWHT stages commute, so partition the 12 index bits into 3 register-held
// groups of 4 bits each; 16-pt in-register FWHT per phase, LDS exchange
// between phases. LDS index padded by (l>>5): all accesses <=2-way bank
// aliasing (free on CDNA4 wave64/32-bank).

#define ROW_N 4096
#define NTHREADS 256

__device__ __forceinline__ int lpad(int l) { return l + (l >> 5); }

__device__ __forceinline__ void fwht16(float x[16]) {
#pragma unroll
    for (int m = 1; m < 16; m <<= 1) {
#pragma unroll
        for (int r = 0; r < 16; ++r) {
            if ((r & m) == 0) {
                const float u = x[r];
                const float v = x[r | m];
                x[r]     = u + v;
                x[r | m] = u - v;
            }
        }
    }
}

__launch_bounds__(NTHREADS)
__global__ void fwht_mul_kernel(const float* __restrict__ a,
                                const float* __restrict__ b,
                                float* __restrict__ out) {
    __shared__ float lds[ROW_N + (ROW_N >> 5)];  // 4224 floats = 16.9 KiB

    const int t = threadIdx.x;
    const long long row = blockIdx.x;
    const float* __restrict__ pa = a + row * ROW_N;
    const float* __restrict__ pb = b + row * ROW_N;
    float* __restrict__ po = out + row * ROW_N;

    float x[16];

    // ---- Phase 1: regs hold element bits {0,1,10,11} ----
    // l1(r,t) = (r&3) | (t<<2) | ((r>>2)<<10). float4 loads: lane-consecutive 16B.
#pragma unroll
    for (int r4 = 0; r4 < 4; ++r4) {
        const int off = (r4 << 10) + (t << 2);
        const float4 va = *reinterpret_cast<const float4*>(pa + off);
        const float4 vb = *reinterpret_cast<const float4*>(pb + off);
        x[r4 * 4 + 0] = va.x * vb.x;
        x[r4 * 4 + 1] = va.y * vb.y;
        x[r4 * 4 + 2] = va.z * vb.z;
        x[r4 * 4 + 3] = va.w * vb.w;
    }
    fwht16(x);  // butterflies over bits 0,1,10,11

    // ---- Exchange 1: to regs = bits {2..5} ----
#pragma unroll
    for (int r = 0; r < 16; ++r) {
        const int l = (r & 3) | (t << 2) | ((r >> 2) << 10);
        lds[lpad(l)] = x[r];
    }
    __syncthreads();
#pragma unroll
    for (int r = 0; r < 16; ++r) {
        const int l = (t & 3) | (r << 2) | ((t >> 2) << 6);
        x[r] = lds[lpad(l)];
    }
    fwht16(x);  // butterflies over bits 2..5

    // ---- Exchange 2: to regs = bits {6..9} ----
    __syncthreads();
#pragma unroll
    for (int r = 0; r < 16; ++r) {
        const int l = (t & 3) | (r << 2) | ((t >> 2) << 6);
        lds[lpad(l)] = x[r];
    }
    __syncthreads();
#pragma unroll
    for (int r = 0; r < 16; ++r) {
        const int l = (t & 63) | (r << 6) | ((t >> 6) << 10);
        x[r] = lds[lpad(l)];
    }
    fwht16(x);  // butterflies over bits 6..9

    // ---- Store (scale = 1/sqrt(4096) = 1/64): lane-consecutive 4B ----
#pragma unroll
    for (int r = 0; r < 16; ++r) {
        const int l = (t & 63) | (r << 6) | ((t >> 6) << 10);
        po[l] = x[r] * 0.015625f;
    }
}

extern "C" void kernel_launch(void* const* d_in, const int* in_sizes, int n_in,
                              void* d_out, int out_size, void* d_ws, size_t ws_size,
                              hipStream_t stream) {
    const float* a = (const float*)d_in[0];
    const float* b = (const float*)d_in[1];
    float* out = (float*)d_out;
    const int rows = in_sizes[0] / ROW_N;  // 8192
    hipLaunchKernelGGL(fwht_mul_kernel, dim3(rows), dim3(NTHREADS), 0, stream,
                       a, b, out);
}

// Round 2
// 63.066 us; speedup vs baseline: 1.2245x; 1.2245x over previous
//
#include <hip/hip_runtime.h>

// out = FWHT(in1 * in2) / sqrt(4096), rows of length N=4096, fp32.
// One row per 256-thread block; 16 elements/thread in registers.
// 12 index bits partitioned into 3 register-held groups of 4; 16-pt
// in-register FWHT per phase, LDS exchange between phases (pad l+(l>>5):
// <=2-way bank aliasing, free on wave64/32-bank).
// R2: non-temporal output stores — output (128 MiB) is never re-read, and
// letting it allocate in L2/L3 evicts the 256 MiB input set that otherwise
// stays Infinity-Cache-resident across timed replays.

#define ROW_N 4096
#define NTHREADS 256

__device__ __forceinline__ int lpad(int l) { return l + (l >> 5); }

__device__ __forceinline__ void fwht16(float x[16]) {
#pragma unroll
    for (int m = 1; m < 16; m <<= 1) {
#pragma unroll
        for (int r = 0; r < 16; ++r) {
            if ((r & m) == 0) {
                const float u = x[r];
                const float v = x[r | m];
                x[r]     = u + v;
                x[r | m] = u - v;
            }
        }
    }
}

__launch_bounds__(NTHREADS)
__global__ void fwht_mul_kernel(const float* __restrict__ a,
                                const float* __restrict__ b,
                                float* __restrict__ out) {
    __shared__ float lds[ROW_N + (ROW_N >> 5)];  // 4224 floats = 16.9 KiB

    const int t = threadIdx.x;
    const long long row = blockIdx.x;
    const float* __restrict__ pa = a + row * ROW_N;
    const float* __restrict__ pb = b + row * ROW_N;
    float* __restrict__ po = out + row * ROW_N;

    float x[16];

    // ---- Phase 1: regs hold element bits {0,1,10,11} ----
#pragma unroll
    for (int r4 = 0; r4 < 4; ++r4) {
        const int off = (r4 << 10) + (t << 2);
        const float4 va = *reinterpret_cast<const float4*>(pa + off);
        const float4 vb = *reinterpret_cast<const float4*>(pb + off);
        x[r4 * 4 + 0] = va.x * vb.x;
        x[r4 * 4 + 1] = va.y * vb.y;
        x[r4 * 4 + 2] = va.z * vb.z;
        x[r4 * 4 + 3] = va.w * vb.w;
    }
    fwht16(x);  // butterflies over bits 0,1,10,11

    // ---- Exchange 1: to regs = bits {2..5} ----
#pragma unroll
    for (int r = 0; r < 16; ++r) {
        const int l = (r & 3) | (t << 2) | ((r >> 2) << 10);
        lds[lpad(l)] = x[r];
    }
    __syncthreads();
#pragma unroll
    for (int r = 0; r < 16; ++r) {
        const int l = (t & 3) | (r << 2) | ((t >> 2) << 6);
        x[r] = lds[lpad(l)];
    }
    fwht16(x);  // butterflies over bits 2..5

    // ---- Exchange 2: to regs = bits {6..9} ----
    __syncthreads();
#pragma unroll
    for (int r = 0; r < 16; ++r) {
        const int l = (t & 3) | (r << 2) | ((t >> 2) << 6);
        lds[lpad(l)] = x[r];
    }
    __syncthreads();
#pragma unroll
    for (int r = 0; r < 16; ++r) {
        const int l = (t & 63) | (r << 6) | ((t >> 6) << 10);
        x[r] = lds[lpad(l)];
    }
    fwht16(x);  // butterflies over bits 6..9

    // ---- Store (scale = 1/64), non-temporal: don't pollute L2/L3 ----
#pragma unroll
    for (int r = 0; r < 16; ++r) {
        const int l = (t & 63) | (r << 6) | ((t >> 6) << 10);
        __builtin_nontemporal_store(x[r] * 0.015625f, po + l);
    }
}

extern "C" void kernel_launch(void* const* d_in, const int* in_sizes, int n_in,
                              void* d_out, int out_size, void* d_ws, size_t ws_size,
                              hipStream_t stream) {
    const float* a = (const float*)d_in[0];
    const float* b = (const float*)d_in[1];
    float* out = (float*)d_out;
    const int rows = in_sizes[0] / ROW_N;  // 8192
    hipLaunchKernelGGL(fwht_mul_kernel, dim3(rows), dim3(NTHREADS), 0, stream,
                       a, b, out);
}